// Round 1
// baseline (88.189 us; speedup 1.0000x reference)
//
#include <hip/hip_runtime.h>

namespace {

constexpr int S_LEN = 2048;
constexpr int H_N   = 8;
constexpr int D_DIM = 64;
constexpr int N_DIM = 32;
constexpr float NLOG2E = -1.4426950408889634f;

// ws layout: agg[(chunk*64 + slot)*1024 + ch], slot 0..31 = aProd[n], slot 32..63 = bAgg[n]
// (phase 2 overwrites slots 32..63 with the prefix state entering that chunk)

__global__ __launch_bounds__(256) void ssm_chunk_agg(
    const float* __restrict__ dtp, const float* __restrict__ up,
    const float* __restrict__ Ap,  const float* __restrict__ Bp,
    float* __restrict__ agg, int L)
{
    const int w    = threadIdx.x >> 6;
    const int lane = threadIdx.x & 63;
    const int W    = blockIdx.x * 4 + w;
    const int bh    = __builtin_amdgcn_readfirstlane(W & 15);   // b*8 + h
    const int chunk = __builtin_amdgcn_readfirstlane(W >> 4);
    const int b = bh >> 3, hh = bh & 7;
    const int d = lane;
    const int ch = bh * 64 + d;

    const float* Arow = Ap + (hh * D_DIM + d) * N_DIM;
    float Aneg[N_DIM];
#pragma unroll
    for (int n = 0; n < N_DIM; ++n) Aneg[n] = NLOG2E * Arow[n];

    float aP[N_DIM], bA[N_DIM];
#pragma unroll
    for (int n = 0; n < N_DIM; ++n) { aP[n] = 1.0f; bA[n] = 0.0f; }

    const int base_ud = b * (S_LEN * H_N * D_DIM) + hh * D_DIM + d;
    const int base_bc = b * (S_LEN * H_N * N_DIM) + hh * N_DIM;
    const int s0 = chunk * L;

    for (int t = 0; t < L; ++t) {
        const int s = s0 + t;
        const float dtv = dtp[base_ud + s * (H_N * D_DIM)];
        const float uv  = up [base_ud + s * (H_N * D_DIM)];
        const float kk  = dtv * uv;
        const float4* B4 = reinterpret_cast<const float4*>(Bp + base_bc + s * (H_N * N_DIM));
        float Br[N_DIM];
#pragma unroll
        for (int j = 0; j < 8; ++j) {
            float4 v = B4[j];
            Br[4*j+0] = v.x; Br[4*j+1] = v.y; Br[4*j+2] = v.z; Br[4*j+3] = v.w;
        }
#pragma unroll
        for (int n = 0; n < N_DIM; ++n) {
            const float e = __builtin_amdgcn_exp2f(dtv * Aneg[n]);
            aP[n] = aP[n] * e;
            bA[n] = fmaf(e, bA[n], kk * Br[n]);
        }
    }

    const int aggbase = chunk * (64 * 1024) + ch;
#pragma unroll
    for (int n = 0; n < N_DIM; ++n) {
        agg[aggbase + n * 1024]        = aP[n];
        agg[aggbase + (32 + n) * 1024] = bA[n];
    }
}

__global__ __launch_bounds__(256) void ssm_chunk_scan(
    float* __restrict__ agg, int NC)
{
    const int T  = blockIdx.x * 256 + threadIdx.x;   // 32768 threads
    const int ch = T & 1023;
    const int n  = (T >> 10) & 31;
    float p = 0.0f;
    for (int k = 0; k < NC; ++k) {
        const int base = k * (64 * 1024) + ch;
        const float a  = agg[base + n * 1024];
        const float bb = agg[base + (32 + n) * 1024];
        agg[base + (32 + n) * 1024] = p;   // prefix state entering chunk k
        p = fmaf(a, p, bb);
    }
}

__global__ __launch_bounds__(256) void ssm_chunk_out(
    const float* __restrict__ dtp, const float* __restrict__ up,
    const float* __restrict__ Ap,  const float* __restrict__ Bp,
    const float* __restrict__ Cp,  const float* __restrict__ Dp,
    const float* __restrict__ agg, float* __restrict__ outp, int L)
{
    const int w    = threadIdx.x >> 6;
    const int lane = threadIdx.x & 63;
    const int W    = blockIdx.x * 4 + w;
    const int bh    = __builtin_amdgcn_readfirstlane(W & 15);
    const int chunk = __builtin_amdgcn_readfirstlane(W >> 4);
    const int b = bh >> 3, hh = bh & 7;
    const int d = lane;
    const int ch = bh * 64 + d;

    const float* Arow = Ap + (hh * D_DIM + d) * N_DIM;
    float Aneg[N_DIM];
#pragma unroll
    for (int n = 0; n < N_DIM; ++n) Aneg[n] = NLOG2E * Arow[n];

    float h[N_DIM];
    {
        const int aggbase = chunk * (64 * 1024) + ch;
#pragma unroll
        for (int n = 0; n < N_DIM; ++n) h[n] = agg[aggbase + (32 + n) * 1024];
    }

    const float Dv = Dp[hh];
    const int base_ud = b * (S_LEN * H_N * D_DIM) + hh * D_DIM + d;
    const int base_bc = b * (S_LEN * H_N * N_DIM) + hh * N_DIM;
    const int s0 = chunk * L;

    for (int t = 0; t < L; ++t) {
        const int s = s0 + t;
        const float dtv = dtp[base_ud + s * (H_N * D_DIM)];
        const float uv  = up [base_ud + s * (H_N * D_DIM)];
        const float kk  = dtv * uv;
        const float4* B4 = reinterpret_cast<const float4*>(Bp + base_bc + s * (H_N * N_DIM));
        const float4* C4 = reinterpret_cast<const float4*>(Cp + base_bc + s * (H_N * N_DIM));
        float Br[N_DIM], Cr[N_DIM];
#pragma unroll
        for (int j = 0; j < 8; ++j) {
            float4 v = B4[j];
            Br[4*j+0] = v.x; Br[4*j+1] = v.y; Br[4*j+2] = v.z; Br[4*j+3] = v.w;
            float4 c = C4[j];
            Cr[4*j+0] = c.x; Cr[4*j+1] = c.y; Cr[4*j+2] = c.z; Cr[4*j+3] = c.w;
        }
        float yacc[4];
        yacc[0] = Dv * uv; yacc[1] = 0.0f; yacc[2] = 0.0f; yacc[3] = 0.0f;
#pragma unroll
        for (int n = 0; n < N_DIM; ++n) {
            const float e = __builtin_amdgcn_exp2f(dtv * Aneg[n]);
            h[n] = fmaf(e, h[n], kk * Br[n]);
            yacc[n & 3] = fmaf(h[n], Cr[n], yacc[n & 3]);
        }
        outp[base_ud + s * (H_N * D_DIM)] = (yacc[0] + yacc[1]) + (yacc[2] + yacc[3]);
    }
}

} // namespace

extern "C" void kernel_launch(void* const* d_in, const int* in_sizes, int n_in,
                              void* d_out, int out_size, void* d_ws, size_t ws_size,
                              hipStream_t stream)
{
    const float* u  = (const float*)d_in[0];
    const float* dt = (const float*)d_in[1];
    const float* A  = (const float*)d_in[2];
    const float* B  = (const float*)d_in[3];
    const float* C  = (const float*)d_in[4];
    const float* D  = (const float*)d_in[5];
    float* out = (float*)d_out;
    float* agg = (float*)d_ws;

    // choose largest chunk count that fits the workspace: NC * 64 slots * 1024 ch * 4B
    int NC = 128;
    while (NC > 1 && (size_t)NC * 64 * 1024 * sizeof(float) > ws_size) NC >>= 1;
    const int L = S_LEN / NC;

    dim3 blk(256);
    ssm_chunk_agg <<<dim3(NC * 4), blk, 0, stream>>>(dt, u, A, B, agg, L);
    ssm_chunk_scan<<<dim3(128),    blk, 0, stream>>>(agg, NC);
    ssm_chunk_out <<<dim3(NC * 4), blk, 0, stream>>>(dt, u, A, B, C, D, agg, out, L);
}

// Round 2
// 59.927 us; speedup vs baseline: 1.4716x; 1.4716x over previous
//
#include <hip/hip_runtime.h>

namespace {

constexpr int S_LEN = 2048;
constexpr int H_N   = 8;
constexpr int D_DIM = 64;
constexpr int N_DIM = 32;
constexpr float NLOG2E = -1.4426950408889634f;

// ws layout:
//   agg : [chunk][slot 0..63][ch 0..1023]  slot 0..31 = aProd[n], 32..63 = bAgg[n]
//   pref: [chunk][n 0..31 ][ch 0..1023]    prefix state entering chunk
// agg chunk stride = 65536 floats; pref chunk stride = 32768 floats.

template<int L>
__global__ __launch_bounds__(256) void ssm_chunk_agg(
    const float* __restrict__ dtp, const float* __restrict__ up,
    const float* __restrict__ Ap,  const float* __restrict__ Bp,
    float* __restrict__ agg)
{
    const int w    = threadIdx.x >> 6;
    const int lane = threadIdx.x & 63;
    const int W    = blockIdx.x * 4 + w;
    const int bh    = __builtin_amdgcn_readfirstlane(W & 15);   // b*8 + h
    const int chunk = __builtin_amdgcn_readfirstlane(W >> 4);
    const int b = bh >> 3, hh = bh & 7;
    const int d = lane;
    const int ch = bh * 64 + d;

    const float* Arow = Ap + (hh * D_DIM + d) * N_DIM;
    float Aneg[N_DIM];
#pragma unroll
    for (int n = 0; n < N_DIM; ++n) Aneg[n] = NLOG2E * Arow[n];

    float aP[N_DIM], bA[N_DIM];
#pragma unroll
    for (int n = 0; n < N_DIM; ++n) { aP[n] = 1.0f; bA[n] = 0.0f; }

    const int base_ud = b * (S_LEN * H_N * D_DIM) + hh * D_DIM + d;
    const int base_bc = b * (S_LEN * H_N * N_DIM) + hh * N_DIM;
    const int s0 = chunk * L;

#pragma unroll 4
    for (int t = 0; t < L; ++t) {
        const int s = s0 + t;
        const float dtv = dtp[base_ud + s * (H_N * D_DIM)];
        const float uv  = up [base_ud + s * (H_N * D_DIM)];
        const float kk  = dtv * uv;
        const float4* B4 = reinterpret_cast<const float4*>(Bp + base_bc + s * (H_N * N_DIM));
        float Br[N_DIM];
#pragma unroll
        for (int j = 0; j < 8; ++j) {
            float4 v = B4[j];
            Br[4*j+0] = v.x; Br[4*j+1] = v.y; Br[4*j+2] = v.z; Br[4*j+3] = v.w;
        }
#pragma unroll
        for (int n = 0; n < N_DIM; ++n) {
            const float e = __builtin_amdgcn_exp2f(dtv * Aneg[n]);
            aP[n] = aP[n] * e;
            bA[n] = fmaf(e, bA[n], kk * Br[n]);
        }
    }

    const int aggbase = chunk * (64 * 1024) + ch;
#pragma unroll
    for (int n = 0; n < N_DIM; ++n) {
        agg[aggbase + n * 1024]        = aP[n];
        agg[aggbase + (32 + n) * 1024] = bA[n];
    }
}

__global__ __launch_bounds__(256) void ssm_chunk_scan(
    const float* __restrict__ agg, float* __restrict__ pref, int NC)
{
    const int T  = blockIdx.x * 256 + threadIdx.x;   // 32768 threads = (n, ch)
    const int ch = T & 1023;
    const int n  = T >> 10;
    const float* ap = agg + n * 1024 + ch;
    const float* bp = agg + (32 + n) * 1024 + ch;
    float*       pp = pref + n * 1024 + ch;

    float p = 0.0f;
    for (int k = 0; k < NC; k += 4) {
        const float a0 = ap[(size_t)(k + 0) * 65536], b0 = bp[(size_t)(k + 0) * 65536];
        const float a1 = ap[(size_t)(k + 1) * 65536], b1 = bp[(size_t)(k + 1) * 65536];
        const float a2 = ap[(size_t)(k + 2) * 65536], b2 = bp[(size_t)(k + 2) * 65536];
        const float a3 = ap[(size_t)(k + 3) * 65536], b3 = bp[(size_t)(k + 3) * 65536];
        pp[(size_t)(k + 0) * 32768] = p; p = fmaf(a0, p, b0);
        pp[(size_t)(k + 1) * 32768] = p; p = fmaf(a1, p, b1);
        pp[(size_t)(k + 2) * 32768] = p; p = fmaf(a2, p, b2);
        pp[(size_t)(k + 3) * 32768] = p; p = fmaf(a3, p, b3);
    }
}

template<int L>
__global__ __launch_bounds__(256) void ssm_chunk_out(
    const float* __restrict__ dtp, const float* __restrict__ up,
    const float* __restrict__ Ap,  const float* __restrict__ Bp,
    const float* __restrict__ Cp,  const float* __restrict__ Dp,
    const float* __restrict__ pref, float* __restrict__ outp)
{
    const int w    = threadIdx.x >> 6;
    const int lane = threadIdx.x & 63;
    const int W    = blockIdx.x * 4 + w;
    const int bh    = __builtin_amdgcn_readfirstlane(W & 15);
    const int chunk = __builtin_amdgcn_readfirstlane(W >> 4);
    const int b = bh >> 3, hh = bh & 7;
    const int d = lane;
    const int ch = bh * 64 + d;

    const float* Arow = Ap + (hh * D_DIM + d) * N_DIM;
    float Aneg[N_DIM];
#pragma unroll
    for (int n = 0; n < N_DIM; ++n) Aneg[n] = NLOG2E * Arow[n];

    float h[N_DIM];
    {
        const int pbase = chunk * (32 * 1024) + ch;
#pragma unroll
        for (int n = 0; n < N_DIM; ++n) h[n] = pref[pbase + n * 1024];
    }

    const float Dv = Dp[hh];
    const int base_ud = b * (S_LEN * H_N * D_DIM) + hh * D_DIM + d;
    const int base_bc = b * (S_LEN * H_N * N_DIM) + hh * N_DIM;
    const int s0 = chunk * L;

#pragma unroll 2
    for (int t = 0; t < L; ++t) {
        const int s = s0 + t;
        const float dtv = dtp[base_ud + s * (H_N * D_DIM)];
        const float uv  = up [base_ud + s * (H_N * D_DIM)];
        const float kk  = dtv * uv;
        const float4* B4 = reinterpret_cast<const float4*>(Bp + base_bc + s * (H_N * N_DIM));
        const float4* C4 = reinterpret_cast<const float4*>(Cp + base_bc + s * (H_N * N_DIM));
        float Br[N_DIM], Cr[N_DIM];
#pragma unroll
        for (int j = 0; j < 8; ++j) {
            float4 v = B4[j];
            Br[4*j+0] = v.x; Br[4*j+1] = v.y; Br[4*j+2] = v.z; Br[4*j+3] = v.w;
            float4 c = C4[j];
            Cr[4*j+0] = c.x; Cr[4*j+1] = c.y; Cr[4*j+2] = c.z; Cr[4*j+3] = c.w;
        }
        float yacc[4];
        yacc[0] = Dv * uv; yacc[1] = 0.0f; yacc[2] = 0.0f; yacc[3] = 0.0f;
#pragma unroll
        for (int n = 0; n < N_DIM; ++n) {
            const float e = __builtin_amdgcn_exp2f(dtv * Aneg[n]);
            h[n] = fmaf(e, h[n], kk * Br[n]);
            yacc[n & 3] = fmaf(h[n], Cr[n], yacc[n & 3]);
        }
        outp[base_ud + s * (H_N * D_DIM)] = (yacc[0] + yacc[1]) + (yacc[2] + yacc[3]);
    }
}

} // namespace

extern "C" void kernel_launch(void* const* d_in, const int* in_sizes, int n_in,
                              void* d_out, int out_size, void* d_ws, size_t ws_size,
                              hipStream_t stream)
{
    const float* u  = (const float*)d_in[0];
    const float* dt = (const float*)d_in[1];
    const float* A  = (const float*)d_in[2];
    const float* B  = (const float*)d_in[3];
    const float* C  = (const float*)d_in[4];
    const float* D  = (const float*)d_in[5];
    float* out = (float*)d_out;

    // pick largest NC whose agg+pref fit: NC * (64+32) * 1024 * 4 bytes
    int NC = 128;
    while (NC > 8 && (size_t)NC * 96 * 1024 * sizeof(float) > ws_size) NC >>= 1;
    const int L = S_LEN / NC;

    float* agg  = (float*)d_ws;
    float* pref = agg + (size_t)NC * 64 * 1024;

    dim3 blk(256);
    switch (L) {
    case 16:
        ssm_chunk_agg<16><<<dim3(NC * 4), blk, 0, stream>>>(dt, u, A, B, agg);
        ssm_chunk_scan  <<<dim3(128),     blk, 0, stream>>>(agg, pref, NC);
        ssm_chunk_out<16><<<dim3(NC * 4), blk, 0, stream>>>(dt, u, A, B, C, D, pref, out);
        break;
    case 32:
        ssm_chunk_agg<32><<<dim3(NC * 4), blk, 0, stream>>>(dt, u, A, B, agg);
        ssm_chunk_scan  <<<dim3(128),     blk, 0, stream>>>(agg, pref, NC);
        ssm_chunk_out<32><<<dim3(NC * 4), blk, 0, stream>>>(dt, u, A, B, C, D, pref, out);
        break;
    default:
        ssm_chunk_agg<64><<<dim3(NC * 4), blk, 0, stream>>>(dt, u, A, B, agg);
        ssm_chunk_scan  <<<dim3(128),     blk, 0, stream>>>(agg, pref, NC);
        ssm_chunk_out<64><<<dim3(NC * 4), blk, 0, stream>>>(dt, u, A, B, C, D, pref, out);
        break;
    }
}